// Round 6
// baseline (373.376 us; speedup 1.0000x reference)
//
#include <hip/hip_runtime.h>
#include <hip/hip_bf16.h>

// ---------------------------------------------------------------------------
// RecursiveSortNet — bf16 MFMA pipeline, u16-key packed bitonic sort:
//   sort: round x to bf16 (monotone => commutes with sort), map to
//         order-preserving u16 keys, 3x bitonic-64 with v_pk_min/max_u16
//   h1 = relu(xs @ W1^T + b1)   bf16 MFMA, fp32 acc
//   h2 = relu(h1 @ W2^T + b2)
//   out =      h2 @ W3^T + b3   fp32 out
//
// R1: sort __syncthreads -> intra-wave lgkmcnt fences. 146 -> 91 us.
// R2: ILP-2, 2 LDS buffers: REGRESSED (118) — occupancy halved.
// R3: ILP-2, 1 shared buffer: 101 us fused.
// R4: direct global stage-in/out; complement trick at k=32. Sort ~<90.
// R5: symmetric transposes (T2 = same perm_write/row_read pair as T1).
// R6: GEMM 2-phase double-buffered pipeline — STAGE(tile t+1) issues
//     BEFORE compute(tile t); ONE __syncthreads per K-iter. HBM latency
//     hides under the current tile's MFMA+ds_read phase (was: full
//     vmcnt0 drain between staging and compute, zero overlap). LDS
//     doubles (48/64 KB) but 2 blocks/CU retained. Sort frozen.
// ---------------------------------------------------------------------------

#define B_DIM 8192
#define D_DIM 4096
#define H1_DIM 512
#define H2_DIM 256

typedef unsigned short u16;
typedef __attribute__((ext_vector_type(2))) unsigned short u16x2;
typedef __attribute__((ext_vector_type(2))) short i16x2;
typedef __attribute__((ext_vector_type(8))) short bf16x8;
typedef __attribute__((ext_vector_type(4))) float f32x4;

// Intra-wave LDS ordering: all prior DS ops complete before anything later
// issues; "memory" clobber stops compiler reordering memory ops across it.
#define WAVE_SYNC() asm volatile("s_waitcnt lgkmcnt(0)" ::: "memory")

__device__ __forceinline__ unsigned short f2bf(float f) {
    union { float f; unsigned u; } v{f};
    unsigned r = v.u + 0x7FFF + ((v.u >> 16) & 1);   // RNE, finite inputs
    return (unsigned short)(r >> 16);
}
// bf16 bits -> order-preserving u16 key
__device__ __forceinline__ u16 fkey(float f) {
    u16 bf = f2bf(f);
    u16 m  = (u16)(((short)bf) >> 15);               // 0xFFFF if negative
    return (u16)(bf ^ (m | 0x8000));
}
__device__ __forceinline__ u16x2 mk2(u16 a, u16 b) { u16x2 r; r.x = a; r.y = b; return r; }

#if defined(__has_builtin) && __has_builtin(__builtin_elementwise_min)
__device__ __forceinline__ u16x2 pkmin(u16x2 a, u16x2 b) { return __builtin_elementwise_min(a, b); }
__device__ __forceinline__ u16x2 pkmax(u16x2 a, u16x2 b) { return __builtin_elementwise_max(a, b); }
#else
__device__ __forceinline__ u16x2 pkmin(u16x2 a, u16x2 b) {
    return mk2(a.x < b.x ? a.x : b.x, a.y < b.y ? a.y : b.y);
}
__device__ __forceinline__ u16x2 pkmax(u16x2 a, u16x2 b) {
    return mk2(a.x > b.x ? a.x : b.x, a.y > b.y ? a.y : b.y);
}
#endif

// Bitonic sort of 64 u16 keys held as 32 packed regs, reg p = (elem p, elem p+32).
// k=32 level: slot-y needs descending; complement y-halves around the level
// (desc merge == asc merge on ~key) so every cross-reg stage is uniform.
__device__ __forceinline__ void sortnet(u16x2 v[32]) {
    const u16x2 cmask = mk2(0, 0xFFFF);
#pragma unroll
    for (int k = 2; k <= 64; k <<= 1) {
        if (k == 32) {
#pragma unroll
            for (int p = 0; p < 32; ++p) v[p] ^= cmask;
        }
#pragma unroll
        for (int j = k >> 1; j >= 1; j >>= 1) {
            if (j == 32) {                     // k==64 only, in-reg x vs y, asc
#pragma unroll
                for (int p = 0; p < 32; ++p) {
                    u16x2 sw = mk2(v[p].y, v[p].x);
                    u16x2 mn = pkmin(v[p], sw), mx = pkmax(v[p], sw);
                    v[p] = mk2(mn.x, mx.y);
                }
            } else {
#pragma unroll
                for (int p = 0; p < 32; ++p) {
                    if (p & j) continue;
                    const int q = p | j;
                    const bool up = ((p & k) == 0);   // slot-uniform (k=32 complemented)
                    u16x2 mn = pkmin(v[p], v[q]), mx = pkmax(v[p], v[q]);
                    v[p] = up ? mn : mx;
                    v[q] = up ? mx : mn;
                }
            }
        }
        if (k == 32) {
#pragma unroll
            for (int p = 0; p < 32; ++p) v[p] ^= cmask;
        }
    }
}

#define SRT 66

// lane c loads column c directly from global (coalesced: 256B per row access)
// and converts to keys, pairs (row r, row r+32).
__device__ __forceinline__ void packkeys(const float* __restrict__ src, int lane, u16x2 v[32]) {
#pragma unroll
    for (int r0 = 0; r0 < 32; r0 += 8) {
        float a[8], b[8];
#pragma unroll
        for (int i = 0; i < 8; ++i) {
            a[i] = src[(r0 + i) * 64 + lane];
            b[i] = src[(r0 + i + 32) * 64 + lane];
        }
#pragma unroll
        for (int i = 0; i < 8; ++i)
            v[r0 + i] = mk2(fkey(a[i]), fkey(b[i]));
    }
}
// lane c stores final sorted column c directly (u16 rows, 128B contiguous).
__device__ __forceinline__ void storeout(u16* __restrict__ dst, int lane, const u16x2 v[32]) {
#pragma unroll
    for (int r = 0; r < 32; ++r) {
        dst[r * 64 + lane]        = v[r].x;
        dst[(r + 32) * 64 + lane] = v[r].y;   // d16_hi store
    }
}

// --- symmetric transpose pair (verified algebra, used for BOTH transposes):
// writer: reg p = (slot x -> LDS-row p, slot y -> LDS-row p+32), position
// pos = (lane&31)*2 + (lane>>5) within the row.
// reader: lane L reads packed b32 pairs from LDS-row L: reg p = (pos 2p, 2p+1).
__device__ __forceinline__ void perm_write(u16* s, int pos, const u16x2 v[32]) {
#pragma unroll
    for (int p = 0; p < 32; ++p) {
        s[p * SRT + pos]        = v[p].x;
        s[(p + 32) * SRT + pos] = v[p].y;
    }
}
__device__ __forceinline__ void row_read(const u16* s, int lane, u16x2 v[32]) {
#pragma unroll
    for (int p = 0; p < 32; ++p)
        v[p] = *(const u16x2*)&s[lane * SRT + p * 2];
}
__device__ __forceinline__ void unmap(u16x2 v[32]) {
#pragma unroll
    for (int p = 0; p < 32; ++p) {
        i16x2 sh = ((i16x2)v[p]) >> 15;        // 0xFFFF where key bit15 set (orig >=0)
        u16x2 m  = (u16x2)sh;
        u16x2 c8; c8.x = 0x8000; c8.y = 0x8000;
        v[p] = v[p] ^ ((~m) | c8);
    }
}

#define SORT_BLOCKS (B_DIM / 4)   // 2048: 2 waves/block, 2 matrices/wave
#define CVT_BLOCKS  512

// Fused: sort blocks [0, SORT_BLOCKS) + weight-cvt blocks [SORT_BLOCKS, +CVT).
__global__ __launch_bounds__(128)
void sort_cvt_kernel(const float* __restrict__ x, u16* __restrict__ xs,
                     const float* __restrict__ W1, unsigned short* __restrict__ W1b,
                     const float* __restrict__ W2, unsigned short* __restrict__ W2b,
                     const float* __restrict__ W3, unsigned short* __restrict__ W3b)
{
    __shared__ u16 smem[2 * 64 * SRT];

    if (blockIdx.x >= SORT_BLOCKS) {
        // ---- weight fp32 -> bf16 conversion (grid-stride) ----
        constexpr int N1 = H1_DIM * D_DIM / 4;
        constexpr int N2 = H2_DIM * H1_DIM / 4;
        constexpr int N3 = D_DIM * H2_DIM / 4;
        constexpr int NT = N1 + N2 + N3;
        int i = (blockIdx.x - SORT_BLOCKS) * 128 + threadIdx.x;
        for (; i < NT; i += CVT_BLOCKS * 128) {
            const float* src; unsigned short* dst; int j;
            if (i < N1)            { src = W1; dst = W1b; j = i; }
            else if (i < N1 + N2)  { src = W2; dst = W2b; j = i - N1; }
            else                   { src = W3; dst = W3b; j = i - N1 - N2; }
            float4 v = ((const float4*)src)[j];
            ushort4 o;
            o.x = f2bf(v.x); o.y = f2bf(v.y); o.z = f2bf(v.z); o.w = f2bf(v.w);
            ((ushort4*)dst)[j] = o;
        }
        return;
    }

    const int wave = threadIdx.x >> 6;
    const int lane = threadIdx.x & 63;
    u16* s = smem + wave * 64 * SRT;           // exclusive per-wave buffer
    const size_t m0 = (size_t)blockIdx.x * 4 + wave * 2;   // matrices m0, m0+1
    const float* srcA = x  + m0 * D_DIM;
    const float* srcB = srcA + D_DIM;
    u16*         dstA = xs + m0 * D_DIM;
    u16*         dstB = dstA + D_DIM;

    const int pos = (lane & 31) * 2 + (lane >> 5);   // permuted position

    u16x2 va[32], vb[32];

    // ---- sort 1 (columns): direct global stage-in, no LDS ----
    packkeys(srcA, lane, va);
    sortnet(va);
    packkeys(srcB, lane, vb);
    perm_write(s, pos, va);      // T1 A
    sortnet(vb);                 // covers A's write drain
    WAVE_SYNC();
    row_read(s, lane, va);
    WAVE_SYNC();                 // A reads done -> buffer free
    perm_write(s, pos, vb);      // T1 B
    sortnet(va);                 // sort 2 A (rows)  || B's writes drain
    WAVE_SYNC();
    row_read(s, lane, vb);
    WAVE_SYNC();
    perm_write(s, pos, va);      // T2 A (same code by symmetry)
    sortnet(vb);                 // sort 2 B  || A's writes drain
    WAVE_SYNC();
    row_read(s, lane, va);
    WAVE_SYNC();
    perm_write(s, pos, vb);      // T2 B
    sortnet(va);                 // sort 3 A (columns)  || B's writes drain
    unmap(va);
    storeout(dstA, lane, va);    // direct global stage-out A
    WAVE_SYNC();
    row_read(s, lane, vb);
    sortnet(vb);                 // sort 3 B
    unmap(vb);
    storeout(dstB, lane, vb);    // direct global stage-out B
}

// ---------------- bf16 MFMA GEMM: C = act(A @ W^T + bias) ------------------
// 2-phase double-buffered K-loop: STAGE(tile t+1) issues BEFORE compute of
// tile t; one __syncthreads per iter (its vmcnt0+lgkmcnt0 drain makes the
// next tile ready AND retires this tile's reads -> WAR-safe buffer swap).
// Grid is (M/BM, N/BN): A-panel siblings share an XCD (L2 locality).
template<int BM, int BN, bool RELU, bool OUT_BF16>
__global__ __launch_bounds__(256, 2)
void gemm_mfma(const unsigned short* __restrict__ A,
               const unsigned short* __restrict__ Wt,
               const float* __restrict__ bias,
               void* __restrict__ Cout, int M, int N, int K)
{
    constexpr int BK  = 64;
    constexpr int WTM = BM / 2, WTN = BN / 2;
    constexpr int FM  = WTM / 16, FN = WTN / 16;
    __shared__ unsigned short sA[2][BM * BK];
    __shared__ unsigned short sB[2][BN * BK];

    const int tid  = threadIdx.x;
    const int wave = tid >> 6;
    const int lane = tid & 63;
    const int wm   = wave >> 1, wn = wave & 1;
    const int gm0  = blockIdx.x * BM;
    const int gn0  = blockIdx.y * BN;

    const int r_in = lane >> 3;
    const int j_in = lane & 7;

    f32x4 acc[FM][FN] = {};

    const int nt = K / BK;

    // ---- prologue: stage tile 0 into buffer 0 ----
    {
#pragma unroll
        for (int c = 0; c < BM / 32; ++c) {
            int rb  = wave * (BM / 4) + c * 8;
            int r   = rb + r_in;
            int seg = j_in ^ (r & 7);
            const unsigned short* g = A + (size_t)(gm0 + r) * K + seg * 8;
            __builtin_amdgcn_global_load_lds(
                (const __attribute__((address_space(1))) void*)g,
                (__attribute__((address_space(3))) void*)&sA[0][rb * 64],
                16, 0, 0);
        }
#pragma unroll
        for (int c = 0; c < BN / 32; ++c) {
            int rb  = wave * (BN / 4) + c * 8;
            int r   = rb + r_in;
            int seg = j_in ^ (r & 7);
            const unsigned short* g = Wt + (size_t)(gn0 + r) * K + seg * 8;
            __builtin_amdgcn_global_load_lds(
                (const __attribute__((address_space(1))) void*)g,
                (__attribute__((address_space(3))) void*)&sB[0][rb * 64],
                16, 0, 0);
        }
    }
    __syncthreads();

    for (int t = 0; t < nt; ++t) {
        const int cur = t & 1;
        // ---- issue next tile's staging (overlaps this tile's compute) ----
        if (t + 1 < nt) {
            const int nxt = cur ^ 1;
            const int k0  = (t + 1) * BK;
#pragma unroll
            for (int c = 0; c < BM / 32; ++c) {
                int rb  = wave * (BM / 4) + c * 8;
                int r   = rb + r_in;
                int seg = j_in ^ (r & 7);
                const unsigned short* g = A + (size_t)(gm0 + r) * K + k0 + seg * 8;
                __builtin_amdgcn_global_load_lds(
                    (const __attribute__((address_space(1))) void*)g,
                    (__attribute__((address_space(3))) void*)&sA[nxt][rb * 64],
                    16, 0, 0);
            }
#pragma unroll
            for (int c = 0; c < BN / 32; ++c) {
                int rb  = wave * (BN / 4) + c * 8;
                int r   = rb + r_in;
                int seg = j_in ^ (r & 7);
                const unsigned short* g = Wt + (size_t)(gn0 + r) * K + k0 + seg * 8;
                __builtin_amdgcn_global_load_lds(
                    (const __attribute__((address_space(1))) void*)g,
                    (__attribute__((address_space(3))) void*)&sB[nxt][rb * 64],
                    16, 0, 0);
            }
        }

        // ---- compute current tile ----
#pragma unroll
        for (int ks = 0; ks < 2; ++ks) {
            bf16x8 afr[FM], bfr[FN];
#pragma unroll
            for (int i = 0; i < FM; ++i) {
                int m   = wm * WTM + i * 16 + (lane & 15);
                int seg = (ks * 4 + (lane >> 4)) ^ (m & 7);
                afr[i] = *(const bf16x8*)&sA[cur][m * 64 + seg * 8];
            }
#pragma unroll
            for (int j = 0; j < FN; ++j) {
                int n   = wn * WTN + j * 16 + (lane & 15);
                int seg = (ks * 4 + (lane >> 4)) ^ (n & 7);
                bfr[j] = *(const bf16x8*)&sB[cur][n * 64 + seg * 8];
            }
#pragma unroll
            for (int i = 0; i < FM; ++i)
#pragma unroll
                for (int j = 0; j < FN; ++j)
                    acc[i][j] = __builtin_amdgcn_mfma_f32_16x16x32_bf16(
                        afr[i], bfr[j], acc[i][j], 0, 0, 0);
        }

        // one barrier per iter: drains next-tile staging (vmcnt0) and
        // retires this tile's ds_reads across all waves (WAR-safe swap).
        __syncthreads();
    }

#pragma unroll
    for (int j = 0; j < FN; ++j) {
        int n = gn0 + wn * WTN + j * 16 + (lane & 15);
        float bv = bias[n];
#pragma unroll
        for (int i = 0; i < FM; ++i) {
#pragma unroll
            for (int r = 0; r < 4; ++r) {
                int m = gm0 + wm * WTM + i * 16 + (lane >> 4) * 4 + r;
                float v = acc[i][j][r] + bv;
                if (RELU) v = fmaxf(v, 0.f);
                if (OUT_BF16)
                    ((unsigned short*)Cout)[(size_t)m * N + n] = f2bf(v);
                else
                    ((float*)Cout)[(size_t)m * N + n] = v;
            }
        }
    }
}

// ---------------------------------------------------------------------------
extern "C" void kernel_launch(void* const* d_in, const int* in_sizes, int n_in,
                              void* d_out, int out_size, void* d_ws, size_t ws_size,
                              hipStream_t stream)
{
    const float* x  = (const float*)d_in[0];
    const float* W1 = (const float*)d_in[1];
    const float* b1 = (const float*)d_in[2];
    const float* W2 = (const float*)d_in[3];
    const float* b2 = (const float*)d_in[4];
    const float* W3 = (const float*)d_in[5];
    const float* b3 = (const float*)d_in[6];
    float* out = (float*)d_out;

    // xs (bf16, 64 MB) lives in d_out; GEMM3 overwrites d_out after GEMM1 read xs.
    u16* xs = (u16*)d_out;
    char* ws = (char*)d_ws;
    unsigned short* h1b = (unsigned short*)(ws);                      //  8 MB
    unsigned short* h2b = (unsigned short*)(ws + (8u  << 20));        //  4 MB
    unsigned short* W1b = (unsigned short*)(ws + (12u << 20));        //  4 MB
    unsigned short* W2b = (unsigned short*)(ws + (16u << 20));        //  0.25 MB
    unsigned short* W3b = (unsigned short*)(ws + (17u << 20));        //  2 MB

    sort_cvt_kernel<<<SORT_BLOCKS + CVT_BLOCKS, 128, 0, stream>>>(
        x, xs, W1, W1b, W2, W2b, W3, W3b);

    // h1 = relu(xs @ W1^T + b1)  [8192 x 512, K=4096]  tile 128x64
    gemm_mfma<128, 64, true, true>
        <<<dim3(B_DIM / 128, H1_DIM / 64), 256, 0, stream>>>(
            xs, W1b, b1, h1b, B_DIM, H1_DIM, D_DIM);

    // h2 = relu(h1 @ W2^T + b2)  [8192 x 256, K=512]   tile 128x64
    gemm_mfma<128, 64, true, true>
        <<<dim3(B_DIM / 128, H2_DIM / 64), 256, 0, stream>>>(
            h1b, W2b, b2, h2b, B_DIM, H2_DIM, H1_DIM);

    // out = h2 @ W3^T + b3       [8192 x 4096, K=256]  tile 128x128
    gemm_mfma<128, 128, false, false>
        <<<dim3(B_DIM / 128, D_DIM / 128), 256, 0, stream>>>(
            h2b, W3b, b3, out, B_DIM, D_DIM, H2_DIM);
}